// Round 6
// baseline (359.828 us; speedup 1.0000x reference)
//
#include <hip/hip_runtime.h>
#include <stdint.h>
#include <stddef.h>

#define DIMC 1024
#define LSEQ 2048
#define BSZ  4
#define DFFC 4096
#define NTOK (BSZ*LSEQ)   // 8192 tokens
#define NCHUNK 32
#define CHUNK 64          // NCHUNK*CHUNK == LSEQ

typedef __bf16 bf16x8 __attribute__((ext_vector_type(8)));
typedef float  f32x4  __attribute__((ext_vector_type(4)));

__device__ __forceinline__ unsigned short f2bf(float f) {
  unsigned int u = __float_as_uint(f);
  u += 0x7fffu + ((u >> 16) & 1u);      // RNE
  return (unsigned short)(u >> 16);
}

__device__ __forceinline__ void async16(const void* g, void* l) {
  __builtin_amdgcn_global_load_lds(
      (const __attribute__((address_space(1))) unsigned int*)(uintptr_t)g,
      (__attribute__((address_space(3))) unsigned int*)(uintptr_t)l,
      16, 0, 0);
}

#define MFMA_BF16 __builtin_amdgcn_mfma_f32_16x16x32_bf16

// ---------------- prep: transposes + LN1 stats + tokstat zero, one launch ----
__global__ __launch_bounds__(256) void prep(const float* __restrict__ w1,
                                            const float* __restrict__ w2,
                                            unsigned short* __restrict__ w1t,
                                            unsigned short* __restrict__ w2t,
                                            const float* __restrict__ x,
                                            float* __restrict__ mu,
                                            float* __restrict__ rstd,
                                            float* __restrict__ tokstat) {
  __shared__ float tile[32][33];
  __shared__ float sh[8];
  const int blk = blockIdx.x;
  if (blk < 8192) {
    const float* w; unsigned short* wt; int K, N, bi;
    if (blk < 4096) { w = w1; wt = w1t; K = DIMC; N = DFFC; bi = blk; }
    else            { w = w2; wt = w2t; K = DFFC; N = DIMC; bi = blk - 4096; }
    const int nbx = N / 32;
    const int n0 = (bi % nbx) * 32, k0 = (bi / nbx) * 32;
    const int tx = threadIdx.x & 31, ty = threadIdx.x >> 5;  // 32 x 8
    #pragma unroll
    for (int i = 0; i < 32; i += 8)
      tile[ty + i][tx] = w[(size_t)(k0 + ty + i) * N + n0 + tx];
    __syncthreads();
    #pragma unroll
    for (int i = 0; i < 32; i += 8)
      wt[(size_t)(n0 + ty + i) * K + k0 + tx] = f2bf(tile[tx][ty + i]);
  } else {
    const int token = blk - 8192;
    const float4* xp = (const float4*)(x + (size_t)token * DIMC);
    float4 v = xp[threadIdx.x];
    float s  = v.x + v.y + v.z + v.w;
    float s2 = v.x*v.x + v.y*v.y + v.z*v.z + v.w*v.w;
    #pragma unroll
    for (int o = 32; o; o >>= 1) { s += __shfl_down(s, o); s2 += __shfl_down(s2, o); }
    const int lane = threadIdx.x & 63, w = threadIdx.x >> 6;
    if (lane == 0) { sh[w] = s; sh[4 + w] = s2; }
    __syncthreads();
    if (threadIdx.x == 0) {
      float ts  = sh[0] + sh[1] + sh[2] + sh[3];
      float ts2 = sh[4] + sh[5] + sh[6] + sh[7];
      float m = ts * (1.f / DIMC);
      float var = ts2 * (1.f / DIMC) - m * m;
      mu[token] = m;
      rstd[token] = rsqrtf(var + 1e-5f);
      tokstat[2 * token] = 0.f;
      tokstat[2 * token + 1] = 0.f;
    }
  }
}

// ---------------- spiral scan ----------------
__device__ __forceinline__ void get_p(const float* __restrict__ phazor, int d,
                                      float& p_re, float& p_im) {
  float pre = phazor[2 * d], pim = phazor[2 * d + 1];
  float a = sqrtf(pre * pre + pim * pim);
  float sc = expf(-a) / a;
  p_re = pre * sc;
  p_im = pim * sc;
}

__global__ __launch_bounds__(256) void scan_phase1(const float* __restrict__ x,
                                                   const float* __restrict__ mu,
                                                   const float* __restrict__ rstd,
                                                   const float* __restrict__ g,
                                                   const float* __restrict__ bb,
                                                   const float* __restrict__ phazor,
                                                   float* __restrict__ Sre,
                                                   float* __restrict__ Sim) {
  const int d = blockIdx.x * 256 + threadIdx.x;
  const int c = blockIdx.y;
  const int b = blockIdx.z;
  float p_re, p_im; get_p(phazor, d, p_re, p_im);
  const float gd = g[d], bd = bb[d];
  const int t0 = c * CHUNK;
  const float* xp  = x + ((size_t)(b * LSEQ + t0)) * DIMC + d;
  const float* mup = mu + b * LSEQ + t0;
  const float* rp  = rstd + b * LSEQ + t0;
  float r_re = 0.f, r_im = 0.f;
  #pragma unroll
  for (int s8 = 0; s8 < CHUNK; s8 += 8) {
    float xv[8];
    #pragma unroll
    for (int k = 0; k < 8; ++k) xv[k] = xp[(size_t)(s8 + k) * DIMC];
    #pragma unroll
    for (int k = 0; k < 8; ++k) {
      float hv = (xv[k] - mup[s8 + k]) * rp[s8 + k] * gd + bd;
      float nr = p_re * r_re - p_im * r_im + hv;
      float ni = p_re * r_im + p_im * r_re;
      r_re = nr; r_im = ni;
    }
  }
  const int bd_i = b * DIMC + d;
  Sre[c * (BSZ * DIMC) + bd_i] = r_re;
  Sim[c * (BSZ * DIMC) + bd_i] = r_im;
}

// phase3: per-chunk replay; computes own chunk-prefix from S, writes x2 and
// accumulates per-token (sum,sum^2) for LN2 via wave reduce + atomics.
__global__ __launch_bounds__(256) void scan_phase3(const float* __restrict__ x,
                                                   const float* __restrict__ mu,
                                                   const float* __restrict__ rstd,
                                                   const float* __restrict__ g,
                                                   const float* __restrict__ bb,
                                                   const float* __restrict__ phazor,
                                                   const float* __restrict__ phazor_init,
                                                   const float* __restrict__ last_re,
                                                   const float* __restrict__ last_im,
                                                   const float* __restrict__ Sre,
                                                   const float* __restrict__ Sim,
                                                   float* __restrict__ x2,
                                                   float* __restrict__ tokstat) {
  __shared__ float shs[CHUNK][4], shs2[CHUNK][4];
  const int d = blockIdx.x * 256 + threadIdx.x;
  const int c = blockIdx.y;
  const int b = blockIdx.z;
  const int lane = threadIdx.x & 63, wv = threadIdx.x >> 6;
  float p_re, p_im; get_p(phazor, d, p_re, p_im);
  const float pi_re = phazor_init[2 * d], pi_im = phazor_init[2 * d + 1];
  const float gd = g[d], bd_ = bb[d];
  const int bd_i = b * DIMC + d;
  float br = p_re, bi = p_im;
  #pragma unroll
  for (int i = 0; i < 6; ++i) { float t = br * br - bi * bi; bi = 2.f * br * bi; br = t; }
  float r_re = 0.f, r_im = 0.f;
  for (int j0 = 0; j0 < c; j0 += 8) {
    float sr[8], si[8];
    const int jn = (c - j0 < 8) ? (c - j0) : 8;
    for (int k = 0; k < jn; ++k) {
      sr[k] = Sre[(j0 + k) * (BSZ * DIMC) + bd_i];
      si[k] = Sim[(j0 + k) * (BSZ * DIMC) + bd_i];
    }
    for (int k = 0; k < jn; ++k) {
      float nr = br * r_re - bi * r_im + sr[k];
      float ni = br * r_im + bi * r_re + si[k];
      r_re = nr; r_im = ni;
    }
  }
  float er = 1.f, ei = 0.f;
  {
    float qr = br, qi = bi;
    int e = c;
    while (e) {
      if (e & 1) { float t = er * qr - ei * qi; ei = er * qi + ei * qr; er = t; }
      float t2 = qr * qr - qi * qi; qi = 2.f * qr * qi; qr = t2;
      e >>= 1;
    }
  }
  const float lre = last_re[bd_i], lim = last_im[bd_i];
  float q_re = lre * er - lim * ei;
  float q_im = lre * ei + lim * er;
  const int t0 = c * CHUNK;
  const float* xp  = x + ((size_t)(b * LSEQ + t0)) * DIMC + d;
  const float* mup = mu + b * LSEQ + t0;
  const float* rp  = rstd + b * LSEQ + t0;
  float* op = x2 + ((size_t)(b * LSEQ + t0)) * DIMC + d;
  #pragma unroll
  for (int s8 = 0; s8 < CHUNK; s8 += 8) {
    float xv[8];
    #pragma unroll
    for (int k = 0; k < 8; ++k) xv[k] = xp[(size_t)(s8 + k) * DIMC];
    #pragma unroll
    for (int k = 0; k < 8; ++k) {
      float hv = (xv[k] - mup[s8 + k]) * rp[s8 + k] * gd + bd_;
      float nr = p_re * r_re - p_im * r_im + hv;
      float ni = p_re * r_im + p_im * r_re;
      r_re = nr; r_im = ni;
      float nq = p_re * q_re - p_im * q_im;
      q_im = p_re * q_im + p_im * q_re;
      q_re = nq;
      float opv = pi_re * r_re - pi_im * r_im + q_re + xv[k];
      op[(size_t)(s8 + k) * DIMC] = opv;
      float a1 = opv, a2 = opv * opv;
      #pragma unroll
      for (int o = 32; o; o >>= 1) { a1 += __shfl_xor(a1, o); a2 += __shfl_xor(a2, o); }
      if (lane == 0) { shs[s8 + k][wv] = a1; shs2[s8 + k][wv] = a2; }
    }
  }
  __syncthreads();
  if (threadIdx.x < CHUNK) {
    const int s = threadIdx.x;
    float s1 = shs[s][0] + shs[s][1] + shs[s][2] + shs[s][3];
    float s2 = shs2[s][0] + shs2[s][1] + shs2[s][2] + shs2[s][3];
    const int tok = b * LSEQ + t0 + s;
    atomicAdd(&tokstat[2 * tok], s1);
    atomicAdd(&tokstat[2 * tok + 1], s2);
  }
}

// ---------------- LN2 apply (stats precomputed by phase3) -> bf16 ----------------
__global__ __launch_bounds__(256) void ln_apply(const float* __restrict__ x2,
                                                const float* __restrict__ tokstat,
                                                const float* __restrict__ g,
                                                const float* __restrict__ bb,
                                                unsigned short* __restrict__ out) {
  const int token = blockIdx.x;
  const float s1 = tokstat[2 * token], s2 = tokstat[2 * token + 1];
  const float m = s1 * (1.f / DIMC);
  const float var = s2 * (1.f / DIMC) - m * m;
  const float r = rsqrtf(var + 1e-5f);
  float4 v = ((const float4*)(x2 + (size_t)token * DIMC))[threadIdx.x];
  float4 gv = ((const float4*)g)[threadIdx.x];
  float4 bv = ((const float4*)bb)[threadIdx.x];
  ushort4 o;
  o.x = f2bf((v.x - m) * r * gv.x + bv.x);
  o.y = f2bf((v.y - m) * r * gv.y + bv.y);
  o.z = f2bf((v.z - m) * r * gv.z + bv.z);
  o.w = f2bf((v.w - m) * r * gv.w + bv.w);
  ((ushort4*)(out + (size_t)token * DIMC))[threadIdx.x] = o;
}

// ---------------- m97-structure 128x128 MFMA GEMM ----------------
// A [M][K] bf16, Bt [N][K] bf16. 256 thr, 4 waves 2Mx2N, wave out 64x64.
// BK=64 as two kk-blocks [128][32] us, 16B-group XOR swizzle (src-preswizzled,
// conflict-free, proven r2-r5). Single-buffered 32KB LDS, 2 __syncthreads()
// per K-tile (compiler emits vmcnt/lgkm waits) -> 2-3 blocks/CU; cross-block
// overlap hides the barrier drain (m97/m114 mechanism).
// EPI 0: out bf16 = silu(acc+bias); EPI 1: out f32 = acc+bias+resid.
// Epilogue staged through LDS for coalesced stores (proven r3-r5).
template<int EPI>
__global__ __launch_bounds__(256) void gemm97(const unsigned short* __restrict__ A,
                                              const unsigned short* __restrict__ Bt,
                                              const float* __restrict__ bias,
                                              const float* __restrict__ resid,
                                              void* __restrict__ outp,
                                              int M, int N, int K) {
  __shared__ __align__(16) unsigned short As[2 * 128 * 32];  // [kk][128][32]
  __shared__ __align__(16) unsigned short Bs[2 * 128 * 32];
  const int tid  = threadIdx.x;
  const int lane = tid & 63;
  const int wave = tid >> 6;
  const int wm = (wave & 1) * 64;
  const int wn = (wave >> 1) * 64;
  const int r15 = lane & 15;
  const int cus = ((lane >> 4) ^ ((r15 >> 1) & 3)) * 8;   // swizzled col (us)

  int bid = blockIdx.x;                    // XCD-aware swizzle (grid % 8 == 0)
  const int cpx = gridDim.x >> 3;
  bid = (bid & 7) * cpx + (bid >> 3);
  const int ntn = N >> 7;
  const int tm = (bid / ntn) << 7;
  const int tn = (bid % ntn) << 7;

  f32x4 acc[4][4];
  #pragma unroll
  for (int i = 0; i < 4; ++i)
    #pragma unroll
    for (int j = 0; j < 4; ++j) acc[i][j] = (f32x4){0.f, 0.f, 0.f, 0.f};

  for (int k0 = 0; k0 < K; k0 += 64) {
    __syncthreads();                      // all waves done reading prev tile
    #pragma unroll
    for (int s = 0; s < 4; ++s) {         // 4 A + 4 B async16 per thread
      const int slot = s * 256 + tid;     // 0..1023
      const int kk = slot >> 9;
      const int sl = slot & 511;
      const int row = sl >> 2;
      const int cg = (sl & 3) ^ ((row >> 1) & 3);   // source pre-swizzle
      const size_t gcol = k0 + kk * 32 + cg * 8;
      async16(A  + (size_t)(tm + row) * K + gcol, As + kk * 4096 + (size_t)sl * 8);
      async16(Bt + (size_t)(tn + row) * K + gcol, Bs + kk * 4096 + (size_t)sl * 8);
    }
    __syncthreads();                      // compiler drains vmcnt before barrier
    #pragma unroll
    for (int kk = 0; kk < 2; ++kk) {
      bf16x8 af[4], bv[4];
      #pragma unroll
      for (int mi = 0; mi < 4; ++mi)
        af[mi] = *(const bf16x8*)(As + kk * 4096 + (wm + mi * 16 + r15) * 32 + cus);
      #pragma unroll
      for (int ni = 0; ni < 4; ++ni)
        bv[ni] = *(const bf16x8*)(Bs + kk * 4096 + (wn + ni * 16 + r15) * 32 + cus);
      #pragma unroll
      for (int mi = 0; mi < 4; ++mi)
        #pragma unroll
        for (int ni = 0; ni < 4; ++ni)
          acc[mi][ni] = MFMA_BF16(af[mi], bv[ni], acc[mi][ni], 0, 0, 0);
    }
  }

  // ---- epilogue via LDS (C/D layout: col = lane&15, row = (lane>>4)*4+j) ----
  const int rg = (lane >> 4) * 4;
  float bias_r[4];
  #pragma unroll
  for (int ni = 0; ni < 4; ++ni) bias_r[ni] = bias[tn + wn + ni * 16 + r15];

  __syncthreads();                        // all waves done with staging LDS
  if constexpr (EPI == 0) {
    unsigned short* C = As;               // 128x128 bf16 = 32 KB, key-swizzled
    #pragma unroll
    for (int mi = 0; mi < 4; ++mi)
      #pragma unroll
      for (int ni = 0; ni < 4; ++ni) {
        const int c0 = wn + ni * 16 + r15;
        #pragma unroll
        for (int j = 0; j < 4; ++j) {
          const int r = wm + mi * 16 + rg + j;
          const int key = (((r & 3) ^ ((r >> 2) & 3)) << 4);
          float v = acc[mi][ni][j] + bias_r[ni];
          v = v / (1.f + __expf(-v));
          C[r * 128 + (c0 ^ key)] = f2bf(v);
        }
      }
    __syncthreads();
    #pragma unroll
    for (int i = 0; i < 8; ++i) {
      const int off = i * 2048 + tid * 8;
      const int r = off >> 7;
      const int pc = off & 127;
      const int key = (((r & 3) ^ ((r >> 2) & 3)) << 4);
      bf16x8 v = *(const bf16x8*)(C + off);
      *(bf16x8*)((unsigned short*)outp + (size_t)(tm + r) * N + tn + (pc ^ key)) = v;
    }
  } else {
    float* C = (float*)As;                // 64x128 f32 = 32 KB per half
    #pragma unroll
    for (int h = 0; h < 2; ++h) {
      if (wm == h * 64) {                 // this wave's rows are in half h
        #pragma unroll
        for (int mi = 0; mi < 4; ++mi)
          #pragma unroll
          for (int ni = 0; ni < 4; ++ni) {
            const int c0 = wn + ni * 16 + r15;
            #pragma unroll
            for (int j = 0; j < 4; ++j) {
              const int rl = mi * 16 + rg + j;       // 0..63 local row
              const int key = (((rl & 3) ^ ((rl >> 2) & 3)) << 4);
              C[rl * 128 + (c0 ^ key)] = acc[mi][ni][j] + bias_r[ni];
            }
          }
      }
      __syncthreads();
      #pragma unroll
      for (int i = 0; i < 8; ++i) {
        const int off = i * 1024 + tid * 4;
        const int rl = off >> 7;
        const int pc = off & 127;
        const int key = (((rl & 3) ^ ((rl >> 2) & 3)) << 4);
        f32x4 v = *(const f32x4*)(C + off);
        const size_t gaddr = (size_t)(tm + h * 64 + rl) * N + tn + (pc ^ key);
        f32x4 rv = *(const f32x4*)(resid + gaddr);
        v += rv;
        *(f32x4*)((float*)outp + gaddr) = v;
      }
      __syncthreads();
    }
  }
}

// ---------------- launch ----------------
extern "C" void kernel_launch(void* const* d_in, const int* in_sizes, int n_in,
                              void* d_out, int out_size, void* d_ws, size_t ws_size,
                              hipStream_t stream) {
  const float* x           = (const float*)d_in[0];
  const float* ln_g        = (const float*)d_in[1];
  const float* ln_b        = (const float*)d_in[2];
  const float* phazor      = (const float*)d_in[3];
  const float* phazor_init = (const float*)d_in[4];
  const float* w1          = (const float*)d_in[5];
  const float* b1          = (const float*)d_in[6];
  const float* w2          = (const float*)d_in[7];
  const float* b2          = (const float*)d_in[8];
  const float* last_re     = (const float*)d_in[9];
  const float* last_im     = (const float*)d_in[10];
  float* out = (float*)d_out;
  char* ws = (char*)d_ws;
  const size_t MB = 1ull << 20;

  float* x2  = (float*)(ws);                         // 32 MB
  float* mu1 = (float*)(ws + 32 * MB);               // 32 KB
  float* rs1 = (float*)(ws + 32 * MB + 64 * 1024);
  float* Sre = (float*)(ws + 32 * MB + 256 * 1024);  // 512 KB each
  float* Sim = (float*)(ws + 32 * MB + 768 * 1024);
  float* tokstat = (float*)(ws + 32 * MB + 1280 * 1024);  // 64 KB
  unsigned short* h2  = (unsigned short*)(ws + 35 * MB);   // 16 MB
  unsigned short* hid = (unsigned short*)(ws + 51 * MB);   // 64 MB
  unsigned short* w1t = (unsigned short*)(ws + 115 * MB);  // 8 MB
  unsigned short* w2t = (unsigned short*)(ws + 123 * MB);  // 8 MB

  prep<<<16384, 256, 0, stream>>>(w1, w2, w1t, w2t, x, mu1, rs1, tokstat);
  scan_phase1<<<dim3(DIMC / 256, NCHUNK, BSZ), 256, 0, stream>>>(x, mu1, rs1, ln_g, ln_b,
                                                                 phazor, Sre, Sim);
  scan_phase3<<<dim3(DIMC / 256, NCHUNK, BSZ), 256, 0, stream>>>(x, mu1, rs1, ln_g, ln_b, phazor,
                                                                 phazor_init, last_re, last_im,
                                                                 Sre, Sim, x2, tokstat);
  ln_apply<<<NTOK, 256, 0, stream>>>(x2, tokstat, ln_g, ln_b, h2);

  gemm97<0><<<(NTOK / 128) * (DFFC / 128), 256, 0, stream>>>(h2, w1t, b1, nullptr, hid,
                                                             NTOK, DFFC, DIMC);
  gemm97<1><<<(NTOK / 128) * (DIMC / 128), 256, 0, stream>>>(hid, w2t, b2, x2, out,
                                                             NTOK, DIMC, DFFC);
}